// Round 14
// baseline (139.245 us; speedup 1.0000x reference)
//
#include <hip/hip_runtime.h>
#include <hip/hip_bf16.h>

#define BB 8
#define NP 4096
#define STRIDE 4
#define KNN 32
#define NS (NP/STRIDE)      // 1024
#define NQ (BB*NS)          // 8192
#define DIN 67
#define H1N 128
#define H2N 256
#define WCAP 512            // survivor cap per wave segment

typedef __attribute__((ext_vector_type(8)))  short bf16x8;
typedef __attribute__((ext_vector_type(16))) float f32x16;
typedef __attribute__((ext_vector_type(8)))  short short8;

// ---------- helpers ----------
__device__ __forceinline__ unsigned int f2u(float f) {
    unsigned int b = __float_as_uint(f);
    return (b & 0x80000000u) ? ~b : (b | 0x80000000u);
}
__device__ __forceinline__ short f2bf(float f) {   // RNE float->bf16 bits
    unsigned u = __float_as_uint(f);
    unsigned r = u + 0x7FFFu + ((u >> 16) & 1u);
    return (short)(r >> 16);
}
__device__ __forceinline__ int pack2(float a, float b) {
    return (int)((unsigned short)f2bf(a) | ((unsigned)(unsigned short)f2bf(b) << 16));
}

// ---------- fused: twin-query KNN + gather + MFMA MLP, 1 block = 2 queries ----------
__global__ __launch_bounds__(256) void fused2_kernel(const float* __restrict__ pos,
                                                     const float* __restrict__ x,
                                                     const short* __restrict__ W1T,
                                                     const short* __restrict__ W2T,
                                                     const float* __restrict__ b1,
                                                     const float* __restrict__ b2,
                                                     float* __restrict__ out) {
    __shared__ __align__(16) unsigned long long surv[4096];  // 32 KB: q0 segs 0-3, q1 segs 4-7
    __shared__ unsigned int pvt[2][4];
    __shared__ int cnts[8];
    __shared__ int col_l[64];

    const int t    = threadIdx.x;
    const int w    = t >> 6;
    const int lane = t & 63;
    const int q0   = blockIdx.x * 2;
    const int b    = q0 >> 10;
    const int s0   = q0 & (NS - 1);
    const int qi0  = b * NP + s0 * STRIDE;
    const int qi1  = qi0 + STRIDE;

    // tail outputs for both queries
    if (t < 10) {
        const int qq = t / 5, r = t % 5;
        const int qg = q0 + qq, qig = qq ? qi1 : qi0;
        float* pos_out   = out + (size_t)NQ * H2N;
        float* batch_out = pos_out + (size_t)NQ * 3;
        float* idx_out   = batch_out + NQ;
        if (r < 3)       pos_out[qg*3+r] = pos[qig*3+r];
        else if (r == 3) batch_out[qg] = (float)b;
        else             idx_out[qg]   = (float)qig;
    }

    const float qx0 = pos[qi0*3+0], qy0 = pos[qi0*3+1], qz0 = pos[qi0*3+2];
    const float qx1 = pos[qi1*3+0], qy1 = pos[qi1*3+1], qz1 = pos[qi1*3+2];
    const float q20 = __fadd_rn(__fadd_rn(__fmul_rn(qx0,qx0), __fmul_rn(qy0,qy0)), __fmul_rn(qz0,qz0));
    const float q21 = __fadd_rn(__fadd_rn(__fmul_rn(qx1,qx1), __fmul_rn(qy1,qy1)), __fmul_rn(qz1,qz1));

    // ---- twin distance phase: shared point loads, exact reference rounding ----
    const float* pb = pos + (size_t)b * NP * 3;
    unsigned int myk0[16], myk1[16];
    #pragma unroll
    for (int i = 0; i < 4; ++i) {
        const int u = t + i * 256;
        const float4* pp = (const float4*)(pb + (size_t)u * 12);
        const float4 v0 = pp[0], v1 = pp[1], v2 = pp[2];
        const float px[4] = {v0.x, v0.w, v1.z, v2.y};
        const float py[4] = {v0.y, v1.x, v1.w, v2.z};
        const float pz[4] = {v0.z, v1.y, v2.x, v2.w};
        #pragma unroll
        for (int j = 0; j < 4; ++j) {
            const float p2 = __fadd_rn(__fadd_rn(__fmul_rn(px[j],px[j]), __fmul_rn(py[j],py[j])), __fmul_rn(pz[j],pz[j]));
            const float dt0 = __fadd_rn(__fadd_rn(__fmul_rn(qx0,px[j]), __fmul_rn(qy0,py[j])), __fmul_rn(qz0,pz[j]));
            const float dt1 = __fadd_rn(__fadd_rn(__fmul_rn(qx1,px[j]), __fmul_rn(qy1,py[j])), __fmul_rn(qz1,pz[j]));
            myk0[i*4+j] = f2u(__fsub_rn(__fadd_rn(q20, p2), __fmul_rn(2.0f, dt0)));
            myk1[i*4+j] = f2u(__fsub_rn(__fadd_rn(q21, p2), __fmul_rn(2.0f, dt1)));
        }
    }

    // ---- pivots: wave 0 ladders q0's 64 sample keys, wave 1 ladders q1's ----
    if (w < 2) {
        const unsigned int mk = (w == 0) ? myk0[0] : myk1[0];
        int rank = 0;
        #pragma unroll
        for (int ss = 0; ss < 64; ++ss) {
            const unsigned int ks = (unsigned int)__shfl((int)mk, ss, 64);
            rank += (int)((ks < mk) | ((ks == mk) & (ss < lane)));
        }
        if (rank == 1)  pvt[w][0] = mk;
        if (rank == 3)  pvt[w][1] = mk;
        if (rank == 8)  pvt[w][2] = mk;
        if (rank == 31) pvt[w][3] = mk;   // guarantees C >= 32 per query
    }
    __syncthreads();

    // ---- twin write-first compact at level 0 ----
    int cw0, cw1;
    {
        const unsigned int T0 = pvt[0][0], T1 = pvt[1][0];
        int b0 = 0, b1v = 0;
        #pragma unroll
        for (int i = 0; i < 16; ++i) {
            const int n = 4 * (t + (i >> 2) * 256) + (i & 3);
            const bool p0 = (myk0[i] <= T0);
            const unsigned long long m0 = __ballot(p0);
            if (p0) {
                const int off = b0 + (int)__popcll(m0 & ((1ull << lane) - 1ull));
                if (off < WCAP) surv[(w << 9) + off] = ((unsigned long long)myk0[i] << 32) | (unsigned int)n;
            }
            b0 += (int)__popcll(m0);
            const bool p1 = (myk1[i] <= T1);
            const unsigned long long m1 = __ballot(p1);
            if (p1) {
                const int off = b1v + (int)__popcll(m1 & ((1ull << lane) - 1ull));
                if (off < WCAP) surv[2048 + (w << 9) + off] = ((unsigned long long)myk1[i] << 32) | (unsigned int)n;
            }
            b1v += (int)__popcll(m1);
        }
        cw0 = (b0 < WCAP) ? b0 : WCAP;
        cw1 = (b1v < WCAP) ? b1v : WCAP;
    }
    if (lane == 0) { cnts[w] = cw0; cnts[4 + w] = cw1; }
    __syncthreads();

    int C0 = cnts[0] + cnts[1] + cnts[2] + cnts[3];
    int C1 = cnts[4] + cnts[5] + cnts[6] + cnts[7];

    // ---- rare escalation q0 (block-uniform) ----
    if (C0 < KNN) {
        int lvl;
        for (lvl = 1; lvl < 4; ++lvl) {
            const unsigned int T = pvt[0][lvl];
            int cnt = 0;
            #pragma unroll
            for (int i = 0; i < 16; ++i)
                cnt += (int)__popcll(__ballot(myk0[i] <= T));
            if (lane == 0) cnts[w] = cnt;
            __syncthreads();
            C0 = cnts[0] + cnts[1] + cnts[2] + cnts[3];
            if (C0 >= KNN) break;
            __syncthreads();
        }
        if (lvl > 3) lvl = 3;
        __syncthreads();
        const unsigned int T = pvt[0][lvl];
        int base = 0;
        #pragma unroll
        for (int i = 0; i < 16; ++i) {
            const bool p = (myk0[i] <= T);
            const unsigned long long m = __ballot(p);
            if (p) {
                const int off = base + (int)__popcll(m & ((1ull << lane) - 1ull));
                if (off < WCAP) {
                    const int n = 4 * (t + (i >> 2) * 256) + (i & 3);
                    surv[(w << 9) + off] = ((unsigned long long)myk0[i] << 32) | (unsigned int)n;
                }
            }
            base += (int)__popcll(m);
        }
        cw0 = (base < WCAP) ? base : WCAP;
        if (lane == 0) cnts[w] = cw0;
        __syncthreads();
        C0 = cnts[0] + cnts[1] + cnts[2] + cnts[3];
    }

    // ---- rare escalation q1 (block-uniform) ----
    if (C1 < KNN) {
        int lvl;
        for (lvl = 1; lvl < 4; ++lvl) {
            const unsigned int T = pvt[1][lvl];
            int cnt = 0;
            #pragma unroll
            for (int i = 0; i < 16; ++i)
                cnt += (int)__popcll(__ballot(myk1[i] <= T));
            if (lane == 0) cnts[4 + w] = cnt;
            __syncthreads();
            C1 = cnts[4] + cnts[5] + cnts[6] + cnts[7];
            if (C1 >= KNN) break;
            __syncthreads();
        }
        if (lvl > 3) lvl = 3;
        __syncthreads();
        const unsigned int T = pvt[1][lvl];
        int base = 0;
        #pragma unroll
        for (int i = 0; i < 16; ++i) {
            const bool p = (myk1[i] <= T);
            const unsigned long long m = __ballot(p);
            if (p) {
                const int off = base + (int)__popcll(m & ((1ull << lane) - 1ull));
                if (off < WCAP) {
                    const int n = 4 * (t + (i >> 2) * 256) + (i & 3);
                    surv[2048 + (w << 9) + off] = ((unsigned long long)myk1[i] << 32) | (unsigned int)n;
                }
            }
            base += (int)__popcll(m);
        }
        cw1 = (base < WCAP) ? base : WCAP;
        if (lane == 0) cnts[4 + w] = cw1;
        __syncthreads();
        C1 = cnts[4] + cnts[5] + cnts[6] + cnts[7];
    }

    // ---- pad all 8 segments to multiple of 8 with +inf sentinels ----
    {
        const int p0 = (cw0 + 7) & ~7;
        for (int i = cw0 + lane; i < p0; i += 64) surv[(w << 9) + i] = ~0ull;
        const int p1 = (cw1 + 7) & ~7;
        for (int i = cw1 + lane; i < p1; i += 64) surv[2048 + (w << 9) + i] = ~0ull;
    }
    __syncthreads();

    // ---- rank: waves 0-1 -> q0, waves 2-3 -> q1 ----
    {
        const int half = w >> 1;
        const int tl   = t & 127;
        const unsigned long long* sb = surv + (half << 11);
        const int* cn = cnts + (half << 2);
        const int cs0 = cn[0], cs1 = cn[1], cs2 = cn[2], cs3 = cn[3];
        const int Cq  = cs0 + cs1 + cs2 + cs3;
        const int e1 = cs0, e2 = cs0 + cs1, e3 = cs0 + cs1 + cs2;
        for (int j = tl; j < Cq; j += 128) {
            const int seg = (int)(j >= e1) + (int)(j >= e2) + (int)(j >= e3);
            const int off = j - ((seg == 0) ? 0 : (seg == 1) ? e1 : (seg == 2) ? e2 : e3);
            const unsigned long long v = sb[(seg << 9) + off];
            int rk = 0;
            #pragma unroll 1
            for (int k = 0; k < 4; ++k) {
                const int np = ((cn[k] + 7) & ~7) >> 1;
                const ulonglong2* sp = (const ulonglong2*)(sb + (k << 9));
                #pragma unroll 4
                for (int ss = 0; ss < np; ++ss) {
                    const ulonglong2 pr = sp[ss];
                    rk += (int)(pr.x < v) + (int)(pr.y < v);
                }
            }
            if (rk < KNN)
                col_l[(half << 5) + rk] = b * NP + (int)(unsigned int)(v & 0xFFFFFFFFull);
        }
    }
    __syncthreads();

    // ================= MLP phase (reuses surv LDS) =================
    short* feat = (short*)surv;            // 64 rows x 80 = 10240 B
    short* h1s  = ((short*)surv) + 5120;   // 64 rows x 128 = 16384 B (swizzled slots)

    // gather: row = t>>2 (0..63), part = t&3 -> 16 x-floats each
    {
        const int row = t >> 2, part = t & 3;
        const int c   = col_l[row];
        const float4* xr = (const float4*)(x + (size_t)c * 64 + part * 16);
        short* fr = feat + row * 80 + part * 16;
        #pragma unroll
        for (int i = 0; i < 4; ++i) {
            const float4 v = xr[i];
            *(int*)(fr + i * 4 + 0) = pack2(v.x, v.y);
            *(int*)(fr + i * 4 + 2) = pack2(v.z, v.w);
        }
        if (part == 0) {
            const int qq = row >> 5;
            const float rqx = qq ? qx1 : qx0, rqy = qq ? qy1 : qy0, rqz = qq ? qz1 : qz0;
            short8 o;
            o[0] = f2bf(pos[c*3+0] - rqx);
            o[1] = f2bf(pos[c*3+1] - rqy);
            o[2] = f2bf(pos[c*3+2] - rqz);
            o[3] = 0; o[4] = 0; o[5] = 0; o[6] = 0; o[7] = 0;
            *(short8*)(feat + row * 80 + 64) = o;
            short8 z = {0,0,0,0,0,0,0,0};
            *(short8*)(feat + row * 80 + 72) = z;
        }
    }
    __syncthreads();

    const int lr2 = lane & 31;   // row/channel lane within 32x32 tile
    const int lh  = lane >> 5;   // k-half selector
    const int qq  = w >> 1;      // wave's query
    const int wn  = w & 1;       // wave's N-split within query

    // layer 1: each wave does 2 N-tiles for its query
    {
        bf16x8 a1[5];
        const short* featq = feat + qq * 2560;   // 32 rows x 80
        #pragma unroll
        for (int kt = 0; kt < 5; ++kt)
            a1[kt] = *(const bf16x8*)(featq + lr2 * 80 + 16*kt + 8*lh);

        #pragma unroll
        for (int ntl = 0; ntl < 2; ++ntl) {
            const int nt = wn * 2 + ntl;
            bf16x8 w1f[5];
            #pragma unroll
            for (int kt = 0; kt < 5; ++kt)
                w1f[kt] = *(const bf16x8*)(W1T + ((size_t)(nt*5 + kt) * 64 + lane) * 8);
            const float bv = b1[32*nt + lr2];
            f32x16 acc;
            #pragma unroll
            for (int r = 0; r < 16; ++r) acc[r] = bv;
            #pragma unroll
            for (int kt = 0; kt < 5; ++kt)
                acc = __builtin_amdgcn_mfma_f32_32x32x16_bf16(a1[kt], w1f[kt], acc, 0, 0, 0);
            #pragma unroll
            for (int r = 0; r < 16; ++r) {
                const int i = (r & 3) + 8*(r >> 2) + 4*lh;    // local row (neighbor)
                const int row64 = qq * 32 + i;
                const int c = 32*nt + lr2;                    // channel
                const int adr = row64 * 128 + ((((c >> 3) ^ (i & 15)) << 3) | (c & 7));
                h1s[adr] = f2bf(fmaxf(acc[r], 0.0f));
            }
        }
    }
    __syncthreads();

    // layer 2: each wave does 4 N-tiles for its query; maxpool over 32 rows
    {
        bf16x8 a2[8];
        #pragma unroll
        for (int kt = 0; kt < 8; ++kt) {
            const int slot = 2*kt + lh;
            a2[kt] = *(const bf16x8*)(h1s + (qq*32 + lr2) * 128 + ((slot ^ (lr2 & 15)) << 3));
        }

        #pragma unroll
        for (int ntl = 0; ntl < 4; ++ntl) {
            const int nt = wn * 4 + ntl;
            bf16x8 wf[8];
            #pragma unroll
            for (int kt = 0; kt < 8; ++kt)
                wf[kt] = *(const bf16x8*)(W2T + ((size_t)(nt*8 + kt) * 64 + lane) * 8);
            f32x16 acc;
            #pragma unroll
            for (int r = 0; r < 16; ++r) acc[r] = 0.0f;
            #pragma unroll
            for (int kt = 0; kt < 8; ++kt)
                acc = __builtin_amdgcn_mfma_f32_32x32x16_bf16(a2[kt], wf[kt], acc, 0, 0, 0);

            float m = acc[0];
            #pragma unroll
            for (int r = 1; r < 16; ++r) m = fmaxf(m, acc[r]);
            m = fmaxf(m, __shfl_xor(m, 32, 64));
            m = fmaxf(m + b2[32*nt + lr2], 0.0f);
            if (lane < 32) out[(size_t)(q0 + qq) * H2N + 32*nt + lane] = m;
        }
    }
}

// ---------- merged weight prep: frag-linear bf16 layouts ----------
__global__ __launch_bounds__(64) void prep_w(const float* __restrict__ W1,
                                             const float* __restrict__ W2,
                                             short* __restrict__ W1T,
                                             short* __restrict__ W2T) {
    const int l = threadIdx.x;
    if (blockIdx.x < 20) {
        const int nt = blockIdx.x / 5, t = blockIdx.x % 5;
        const int c  = 32*nt + (l & 31);
        short8 v;
        #pragma unroll
        for (int b = 0; b < 8; ++b) {
            const int k = 16*t + 8*(l >> 5) + b;
            v[b] = (k < DIN) ? f2bf(W1[k * H1N + c]) : (short)0;
        }
        *(short8*)(W1T + ((size_t)(nt*5 + t) * 64 + l) * 8) = v;
    } else {
        const int bb = blockIdx.x - 20;
        const int nt = bb >> 3, t = bb & 7;
        const int c  = 32*nt + (l & 31);
        short8 v;
        #pragma unroll
        for (int b = 0; b < 8; ++b) {
            const int k = 16*t + 8*(l >> 5) + b;
            v[b] = f2bf(W2[k * H2N + c]);
        }
        *(short8*)(W2T + ((size_t)(nt*8 + t) * 64 + l) * 8) = v;
    }
}

extern "C" void kernel_launch(void* const* d_in, const int* in_sizes, int n_in,
                              void* d_out, int out_size, void* d_ws, size_t ws_size,
                              hipStream_t stream) {
    const float* x   = (const float*)d_in[0];
    const float* pos = (const float*)d_in[1];
    const float* W1  = (const float*)d_in[3];
    const float* b1  = (const float*)d_in[4];
    const float* W2  = (const float*)d_in[5];
    const float* b2  = (const float*)d_in[6];
    float* out = (float*)d_out;

    char* ws   = (char*)d_ws;
    short* W1T = (short*)ws;                 // 20480 B
    short* W2T = (short*)(ws + 20480);       // 65536 B

    prep_w<<<84, 64, 0, stream>>>(W1, W2, W1T, W2T);
    fused2_kernel<<<NQ/2, 256, 0, stream>>>(pos, x, W1T, W2T, b1, b2, out);
}